// Round 10
// baseline (361.331 us; speedup 1.0000x reference)
//
#include <hip/hip_runtime.h>
#include <hip/hip_bf16.h>

// AttnBlock: B=8, C=512, N=2048, G=32.
// All GEMMs NT: Out[m][n] = sum_k A[m][k] * Bt[n][k].
// gemm9<MODE,NSUB>: BM=256, BK=32, subtile width 256 (NSUB=2, A-frag reuse -> 2x
// read ratio, S only) or 128 (NSUB=1, 72KB ring -> 2 blocks/CU for qk/v/PV/proj).
// 3-slot LDS ring, true 2-tile-ahead staging, counted gate vmcnt(LPT) + ONE
// barrier per K-tile. Swizzle: 16B-slot ^ (row>>1)&3 (stage pre-swizzled global,
// read same involution). Batch->XCD pinning kept.

typedef __attribute__((ext_vector_type(8))) short short8;
typedef __attribute__((ext_vector_type(4))) float f32x4;
typedef unsigned short u16;

#define LGKM0 asm volatile("s_waitcnt lgkmcnt(0)" ::: "memory")
#define SCB __builtin_amdgcn_sched_barrier(0)

__device__ __forceinline__ u16 f2bf(float f) {
  __hip_bfloat16 h = __float2bfloat16(f);
  return __builtin_bit_cast(u16, h);
}
__device__ __forceinline__ float bf2f(u16 u) {
  return __uint_as_float(((unsigned)u) << 16);
}

__device__ __forceinline__ void gload_lds16(const void* g, void* l) {
  __builtin_amdgcn_global_load_lds((const __attribute__((address_space(1))) void*)g,
                                   (__attribute__((address_space(3))) void*)l, 16, 0, 0);
}

// MODE 0: bf16 out = acc + bias[col]   MODE 1: + bias[row]   MODE 2: * scale
// MODE 3: raw bf16                     MODE 4: f32 + bias[row] + resid
// Grid: 1-D, gid = t*8 + b;  t = by*GX + bx;  m0 = by*256 + b*mOffB; n0 = bx*BNT.
template <int MODE, int NSUB>
__global__ __launch_bounds__(512, 1) void gemm9(
    const u16* __restrict__ A, const u16* __restrict__ Bt, void* __restrict__ OutV,
    const float* __restrict__ bias, const float* __restrict__ resid,
    int K, int lda, int ldb, int ldo, int GX, int mOffB,
    long sA, long sBt, long sOut, long sRes, float scale) {
  constexpr int BNS = (NSUB == 2) ? 256 : 128;  // subtile width
  constexpr int BNT = BNS * NSUB;               // 512 or 128
  constexpr int WM = (NSUB == 2) ? 2 : 4;
  constexpr int WN = 8 / WM;                    // 4 or 2
  constexpr int WROWS = 256 / WM;               // 128 or 64
  constexpr int MF = WROWS / 16;                // 8 or 4
  constexpr int A_EL = 256 * 32;                // 8192 u16
  constexpr int B_EL = BNT * 32;                // 16384 or 4096 u16
  constexpr int SLOT = A_EL + B_EL;             // 24576 or 12288 u16
  constexpr int ACH = 2;                        // A 16B-chunks per thread per tile
  constexpr int BCH = B_EL / 4096;              // 4 or 1
  constexpr int LPT = ACH + BCH;                // 6 or 3

  __shared__ __align__(16) u16 lds[3 * SLOT];   // 144 KB or 72 KB

  const int gid = blockIdx.x;
  const int b = gid & 7;  // batch == XCD
  const int t0 = gid >> 3;
  const int bx = t0 % GX;
  const int by = t0 / GX;
  const u16* Ab = A + (long)b * sA;
  const u16* Bb = Bt + (long)b * sBt;
  const int tid = threadIdx.x;
  const int lane = tid & 63;
  const int wid = tid >> 6;
  const int wr = wid / WN;
  const int wc = wid % WN;
  const int m0 = by * 256 + b * mOffB;
  const int n0 = bx * BNT;
  const int l15 = lane & 15;
  const int lhi = lane >> 4;
  const int sx = (l15 >> 1) & 3;                // read-side slot swizzle term
  const int slotx = lhi ^ sx;                   // effective 16B slot within 64B row

  f32x4 acc[MF][NSUB * 4];
#pragma unroll
  for (int i = 0; i < MF; ++i)
#pragma unroll
    for (int j = 0; j < NSUB * 4; ++j) acc[i][j] = (f32x4){0.f, 0.f, 0.f, 0.f};

  const int T = K / 32;

  auto stage = [&](int kt, int slot) {
    u16* As = lds + (size_t)slot * SLOT;
    u16* Bs = As + A_EL;
#pragma unroll
    for (int i = 0; i < ACH; ++i) {
      const int c = tid + i * 512;
      const int row = c >> 2;
      const int s4 = (c & 3) ^ ((row >> 1) & 3);
      gload_lds16(Ab + (long)(m0 + row) * lda + kt * 32 + s4 * 8, (void*)(As + c * 8));
    }
#pragma unroll
    for (int i = 0; i < BCH; ++i) {
      const int c = tid + i * 512;
      const int row = c >> 2;
      const int s4 = (c & 3) ^ ((row >> 1) & 3);
      gload_lds16(Bb + (long)(n0 + row) * ldb + kt * 32 + s4 * 8, (void*)(Bs + c * 8));
    }
  };

  stage(0, 0);
  stage(1, 1);

  for (int t = 0; t < T; ++t) {
    const int sl = t % 3;
    // gate: own-wave drain of tile t (leave tile t+1's LPT loads in flight)
    if (t + 1 < T) {
      if constexpr (LPT == 6) { asm volatile("s_waitcnt vmcnt(6)" ::: "memory"); }
      else                    { asm volatile("s_waitcnt vmcnt(3)" ::: "memory"); }
    } else {
      asm volatile("s_waitcnt vmcnt(0)" ::: "memory");
    }
    SCB;
    __builtin_amdgcn_s_barrier();  // all waves gated -> tile t fully in LDS; slot(t-1) reads all retired
    SCB;
    if (t + 2 < T) {
      int ns = sl + 2; if (ns >= 3) ns -= 3;
      stage(t + 2, ns);
    }
    const u16* A_ = lds + (size_t)sl * SLOT;
    const u16* B_ = A_ + A_EL;

    short8 bf[NSUB * 4];
#pragma unroll
    for (int s = 0; s < NSUB; ++s)
#pragma unroll
      for (int nf = 0; nf < 4; ++nf)
        bf[s * 4 + nf] = *(const short8*)(B_ + (s * BNS + wc * 64 + nf * 16 + l15) * 32 + slotx * 8);
    short8 af0[MF / 2], af1[MF / 2];
#pragma unroll
    for (int mf = 0; mf < MF / 2; ++mf)
      af0[mf] = *(const short8*)(A_ + (wr * WROWS + mf * 16 + l15) * 32 + slotx * 8);
    LGKM0; SCB;
    // issue second-half A reads; they drain under the first MFMA cluster
#pragma unroll
    for (int mf = 0; mf < MF / 2; ++mf)
      af1[mf] = *(const short8*)(A_ + (wr * WROWS + (MF / 2 + mf) * 16 + l15) * 32 + slotx * 8);
    SCB;
    __builtin_amdgcn_s_setprio(1);
#pragma unroll
    for (int mf = 0; mf < MF / 2; ++mf)
#pragma unroll
      for (int j = 0; j < NSUB * 4; ++j)
        acc[mf][j] = __builtin_amdgcn_mfma_f32_16x16x32_bf16(af0[mf], bf[j], acc[mf][j], 0, 0, 0);
    __builtin_amdgcn_s_setprio(0);
    LGKM0; SCB;
    __builtin_amdgcn_s_setprio(1);
#pragma unroll
    for (int mf = 0; mf < MF / 2; ++mf)
#pragma unroll
      for (int j = 0; j < NSUB * 4; ++j)
        acc[MF / 2 + mf][j] = __builtin_amdgcn_mfma_f32_16x16x32_bf16(af1[mf], bf[j],
                                                                      acc[MF / 2 + mf][j], 0, 0, 0);
    __builtin_amdgcn_s_setprio(0);
    SCB;
  }

  // epilogue: D row=(lane>>4)*4+reg (m), col=lane&15 (n); plain stores (L2-merged)
  const int rbase = m0 + wr * WROWS + lhi * 4;
#pragma unroll
  for (int mf = 0; mf < MF; ++mf) {
#pragma unroll
    for (int s = 0; s < NSUB; ++s) {
#pragma unroll
      for (int nf = 0; nf < 4; ++nf) {
#pragma unroll
        for (int i = 0; i < 4; ++i) {
          const int row = rbase + mf * 16 + i;
          const int col = n0 + s * BNS + wc * 64 + nf * 16 + l15;
          const long oidx = (long)b * sOut + (long)row * ldo + col;
          const float v = acc[mf][s * 4 + nf][i];
          if (MODE == 0) {
            ((u16*)OutV)[oidx] = f2bf(v + bias[col]);
          } else if (MODE == 1) {
            ((u16*)OutV)[oidx] = f2bf(v + bias[row]);
          } else if (MODE == 2) {
            ((u16*)OutV)[oidx] = f2bf(v * scale);
          } else if (MODE == 3) {
            ((u16*)OutV)[oidx] = f2bf(v);
          } else {
            const float r = resid[(long)b * sRes + (long)row * ldo + col];
            ((float*)OutV)[oidx] = v + bias[row] + r;
          }
        }
      }
    }
  }
}

// per-(b,g) mean/rstd over contiguous 16*2048 = 32768 floats
__global__ __launch_bounds__(256) void gn_stats(const float* __restrict__ x,
                                                float* __restrict__ stats) {
  const int bg = blockIdx.x;
  const float4* p4 = (const float4*)(x + (long)bg * 32768);
  float s = 0.f, ss = 0.f;
  for (int i = threadIdx.x; i < 8192; i += 256) {
    const float4 u = p4[i];
    s += (u.x + u.y) + (u.z + u.w);
    ss += (u.x * u.x + u.y * u.y) + (u.z * u.z + u.w * u.w);
  }
#pragma unroll
  for (int off = 32; off > 0; off >>= 1) {
    s += __shfl_xor(s, off, 64);
    ss += __shfl_xor(ss, off, 64);
  }
  __shared__ float rs[4], rss[4];
  const int lane = threadIdx.x & 63, wid = threadIdx.x >> 6;
  if (lane == 0) { rs[wid] = s; rss[wid] = ss; }
  __syncthreads();
  if (threadIdx.x == 0) {
    s = rs[0] + rs[1] + rs[2] + rs[3];
    ss = rss[0] + rss[1] + rss[2] + rss[3];
    const float mean = s * (1.f / 32768.f);
    const float var = ss * (1.f / 32768.f) - mean * mean;
    stats[bg * 2] = mean;
    stats[bg * 2 + 1] = rsqrtf(var + 1e-6f);
  }
}

// normalize + affine, write hT[b][n][c] bf16 (64x64 LDS-tiled transpose)
__global__ __launch_bounds__(256) void gn_apply_t(
    const float* __restrict__ x, const float* __restrict__ stats,
    const float* __restrict__ gamma, const float* __restrict__ beta,
    u16* __restrict__ hT) {
  const int b = blockIdx.z, c0 = blockIdx.y * 64, n0 = blockIdx.x * 64;
  __shared__ u16 t[64][72];
  const int tid = threadIdx.x;
  const float* px = x + ((long)b * 512 + c0) * 2048 + n0;
#pragma unroll
  for (int i = 0; i < 4; ++i) {
    const int idx = tid + i * 256;
    const int r = idx >> 4, q4 = (idx & 15) * 4;
    const float4 u = *(const float4*)(px + (long)r * 2048 + q4);
    const int c = c0 + r, g = c >> 4;
    const float mean = stats[(b * 32 + g) * 2];
    const float rstd = stats[(b * 32 + g) * 2 + 1];
    const float ga = gamma[c] * rstd;
    const float be = beta[c] - mean * ga;
    t[r][q4 + 0] = f2bf(u.x * ga + be);
    t[r][q4 + 1] = f2bf(u.y * ga + be);
    t[r][q4 + 2] = f2bf(u.z * ga + be);
    t[r][q4 + 3] = f2bf(u.w * ga + be);
  }
  __syncthreads();
#pragma unroll
  for (int i = 0; i < 2; ++i) {
    const int idx = tid + i * 256;
    const int nr = idx >> 3, cc = (idx & 7) * 8;
    short8 w;
#pragma unroll
    for (int j = 0; j < 8; ++j) w[j] = (short)t[cc + j][nr];
    *(short8*)(hT + ((long)b * 2048 + n0 + nr) * 512 + c0 + cc) = w;
  }
}

// row softmax in place on bf16 S; gid = r*8 + b, row = b*2048 + r (XCD-pinned)
__global__ __launch_bounds__(256) void softmax_rows(u16* __restrict__ S) {
  const int gid = blockIdx.x;
  const long row = (long)(gid & 7) * 2048 + (gid >> 3);
  u16* p = S + row * 2048;
  const int tid = threadIdx.x;
  const int lane = tid & 63, wid = tid >> 6;
  const short8 raw = *(const short8*)(p + tid * 8);
  float v[8];
#pragma unroll
  for (int j = 0; j < 8; ++j) v[j] = bf2f((u16)raw[j]);
  float m = v[0];
#pragma unroll
  for (int j = 1; j < 8; ++j) m = fmaxf(m, v[j]);
#pragma unroll
  for (int off = 32; off > 0; off >>= 1) m = fmaxf(m, __shfl_xor(m, off, 64));
  __shared__ float redm[4], reds[4];
  if (lane == 0) redm[wid] = m;
  __syncthreads();
  m = fmaxf(fmaxf(redm[0], redm[1]), fmaxf(redm[2], redm[3]));
  float e[8];
  float s = 0.f;
#pragma unroll
  for (int j = 0; j < 8; ++j) {
    e[j] = __expf(v[j] - m);
    s += e[j];
  }
#pragma unroll
  for (int off = 32; off > 0; off >>= 1) s += __shfl_xor(s, off, 64);
  if (lane == 0) reds[wid] = s;
  __syncthreads();
  s = reds[0] + reds[1] + reds[2] + reds[3];
  const float inv = 1.f / s;
  short8 o;
#pragma unroll
  for (int j = 0; j < 8; ++j) o[j] = (short)f2bf(e[j] * inv);
  *(short8*)(p + tid * 8) = o;
}

// convert the 4 fp32 512x512 weights to bf16 (contiguous -> wq|wk|wv|wp)
__global__ __launch_bounds__(256) void cvt_w(const float* __restrict__ w0,
                                             const float* __restrict__ w1,
                                             const float* __restrict__ w2,
                                             const float* __restrict__ w3,
                                             u16* __restrict__ out) {
  const int z = blockIdx.y;
  const float* src = (z == 0) ? w0 : (z == 1) ? w1 : (z == 2) ? w2 : w3;
  const int i = blockIdx.x * 256 + threadIdx.x;
  out[(long)z * 262144 + i] = f2bf(src[i]);
}

// concat bq|bk -> bqk[1024]
__global__ __launch_bounds__(256) void cvt_bias(const float* __restrict__ bq,
                                                const float* __restrict__ bk,
                                                float* __restrict__ bqk) {
  const int i = blockIdx.x * 256 + threadIdx.x;
  bqk[i] = (i < 512) ? bq[i] : bk[i - 512];
}

extern "C" void kernel_launch(void* const* d_in, const int* in_sizes, int n_in,
                              void* d_out, int out_size, void* d_ws, size_t ws_size,
                              hipStream_t stream) {
  const float* x = (const float*)d_in[0];
  const float* gs = (const float*)d_in[1];
  const float* gb = (const float*)d_in[2];
  const float* wq = (const float*)d_in[3];
  const float* bq = (const float*)d_in[4];
  const float* wk = (const float*)d_in[5];
  const float* bk = (const float*)d_in[6];
  const float* wv = (const float*)d_in[7];
  const float* bv = (const float*)d_in[8];
  const float* wp = (const float*)d_in[9];
  const float* bp = (const float*)d_in[10];

  char* ws = (char*)d_ws;
  float* stats = (float*)ws;               // 2 KB
  float* bqk = (float*)(ws + 4096);        // 4 KB
  u16* hT = (u16*)(ws + 8192);             // [16384, 512] bf16, 16 MB
  u16* qkT = hT + 8388608;                 // [16384, 1024] bf16, 32 MB (q|k)
  u16* vv = qkT + 16777216;                // [B, 512, 2048] bf16, 16 MB
  u16* S = vv + 8388608;                   // [B, 2048, 2048] bf16, 64 MB
  u16* wb = S + 33554432;                  // wq|wk|wv|wp bf16, 2 MB
  u16* attnT = hT;                         // alias: hT dead after qk + v GEMMs
  float* out = (float*)d_out;

  cvt_w<<<dim3(1024, 4, 1), 256, 0, stream>>>(wq, wk, wv, wp, wb);
  cvt_bias<<<dim3(4), 256, 0, stream>>>(bq, bk, bqk);
  gn_stats<<<dim3(256), 256, 0, stream>>>(x, stats);
  gn_apply_t<<<dim3(32, 8, 8), 256, 0, stream>>>(x, stats, gs, gb, hT);

  // qk: M=16384 (m0 = by*256 + b*2048), N=1024; per-b 8m x 8n -> 512 blocks (2/CU)
  gemm9<0, 1><<<dim3(512), 512, 0, stream>>>(
      hT, wb, qkT, bqk, nullptr, 512, 512, 512, 1024, 8, 2048, 0, 0, 0, 0, 0.f);
  // v: M=512, N=2048; per-b 2m x 16n -> 256 blocks
  gemm9<1, 1><<<dim3(256), 512, 0, stream>>>(
      wb + 524288, hT, vv, bv, nullptr, 512, 512, 512, 2048, 16, 0, 0, 1048576, 1048576, 0, 0.f);
  // S: M=N=2048, K=512; wide kernel, per-b 8m x 4n(512) -> 256 blocks
  gemm9<2, 2><<<dim3(256), 512, 0, stream>>>(
      qkT, qkT + 512, S, nullptr, nullptr, 512, 1024, 1024, 2048, 4, 0, 2097152, 2097152,
      4194304, 0, 0.04419417382415922f);
  softmax_rows<<<dim3(16384), 256, 0, stream>>>(S);
  // PV: M=2048, N=512, K=2048; per-b 8m x 4n -> 256 blocks
  gemm9<3, 1><<<dim3(256), 512, 0, stream>>>(
      S, vv, attnT, nullptr, nullptr, 2048, 2048, 2048, 512, 4, 0, 4194304, 1048576,
      1048576, 0, 0.f);
  // proj+residual: M=512, N=2048, K=512; per-b 2m x 16n -> 256 blocks
  gemm9<4, 1><<<dim3(256), 512, 0, stream>>>(
      wb + 786432, attnT, out, bp, x, 512, 512, 512, 2048, 16, 0, 0, 1048576, 1048576,
      1048576, 0.f);
}

// Round 11
// 184.564 us; speedup vs baseline: 1.9577x; 1.9577x over previous
//
#include <hip/hip_runtime.h>
#include <hip/hip_bf16.h>

// AttnBlock: B=8, C=512, N=2048, G=32.
// All GEMMs NT: Out[m][n] = sum_k A[m][k] * Bt[n][k].
// gemm10<MODE,BN_>: faithful m201 8-phase template. BM=256, BK=64, 8 waves.
// Iteration = 2 K-tiles (even->slot0, odd->slot1). Per phase:
//   {ds_read frags; stage ONE 16KB half-tile into just-freed space; [counted vmcnt
//    at phases 4/8 only]; barrier; lgkmcnt(0); setprio(1); 16 MFMA; setprio(0); barrier}
// B-halves die in each tile's q0 phase; A-halves at tile end -> staging plan:
//   e.q0:A0(o) e.q1:A1(o) e.q2:B0(e+2) e.q3:B1(e+2)+vmcnt(4)
//   o.q0:A0(e+2) o.q1:A1(e+2) o.q2:B0(o+2) o.q3:B1(o+2)+vmcnt(4)
// Batch->XCD pinning kept (FETCH 74->24.6MB). Plain stores (NT regressed).

typedef __attribute__((ext_vector_type(8))) short short8;
typedef __attribute__((ext_vector_type(4))) float f32x4;
typedef unsigned short u16;

#define LGKM0 asm volatile("s_waitcnt lgkmcnt(0)" ::: "memory")
#define SCB __builtin_amdgcn_sched_barrier(0)
#define PH_MID SCB; __builtin_amdgcn_s_barrier(); LGKM0; SCB
#define PH_END SCB; __builtin_amdgcn_s_barrier(); SCB

__device__ __forceinline__ u16 f2bf(float f) {
  __hip_bfloat16 h = __float2bfloat16(f);
  return __builtin_bit_cast(u16, h);
}
__device__ __forceinline__ float bf2f(u16 u) {
  return __uint_as_float(((unsigned)u) << 16);
}

__device__ __forceinline__ void gload_lds16(const void* g, void* l) {
  __builtin_amdgcn_global_load_lds((const __attribute__((address_space(1))) void*)g,
                                   (__attribute__((address_space(3))) void*)l, 16, 0, 0);
}

// MODE 0: bf16 out = acc + bias[col]   MODE 1: + bias[row]   MODE 2: * scale
// MODE 3: raw bf16                     MODE 4: f32 + bias[row] + resid
// Grid: 1-D, gid = t*8 + b;  t = by*GX + bx;  m0 = by*256 + b*mOffB; n0 = bx*BN_.
template <int MODE, int BN_>
__global__ __launch_bounds__(512) void gemm10(
    const u16* __restrict__ A, const u16* __restrict__ Bt, void* __restrict__ OutV,
    const float* __restrict__ bias, const float* __restrict__ resid,
    int K, int lda, int ldb, int ldo, int GX, int mOffB,
    long sA, long sBt, long sOut, long sRes, float scale) {
  constexpr int WM = (BN_ == 256) ? 2 : 4;
  constexpr int WN = 8 / WM;            // 4 or 2
  constexpr int WROWS = 256 / WM;       // 128 or 64
  constexpr int MF = WROWS / 16;        // 8 or 4
  constexpr int A_EL = 256 * 64;        // 16384 u16 (two 8192 halves)
  constexpr int B_EL = BN_ * 64;        // 16384 or 8192 u16
  constexpr int SLOT = A_EL + B_EL;

  __shared__ __align__(16) u16 lds[2 * SLOT];  // 128 KB or 96 KB

  const int gid = blockIdx.x;
  const int b = gid & 7;  // batch == XCD
  const int t0 = gid >> 3;
  const int bx = t0 % GX;
  const int by = t0 / GX;
  const u16* Ab = A + (long)b * sA;
  const u16* Bb = Bt + (long)b * sBt;
  const int tid = threadIdx.x;
  const int lane = tid & 63;
  const int wid = tid >> 6;
  const int wr = wid / WN;
  const int wc = wid % WN;
  const int m0 = by * 256 + b * mOffB;
  const int n0 = bx * BN_;
  const int l15 = lane & 15;
  const int lhi = lane >> 4;
  const int sl = (l15 & 7) << 4;  // read-side XOR swizzle (bytes)

  f32x4 acc[MF][4];
#pragma unroll
  for (int i = 0; i < MF; ++i)
#pragma unroll
    for (int j = 0; j < 4; ++j) acc[i][j] = (f32x4){0.f, 0.f, 0.f, 0.f};

  const int T = K / 64;
  const int halfT = T / 2;

  // stage one 16KB half-tile (2 x 16B loads/thread)
  auto stA = [&](int t, int half) {
    u16* dst = lds + (size_t)(t & 1) * SLOT + half * 8192;
#pragma unroll
    for (int i = 0; i < 2; ++i) {
      const int c = tid + i * 512;
      const int row = c >> 3;  // 0..127 within half
      const int kb = ((c & 7) << 4) ^ ((row & 7) << 4);
      gload_lds16(Ab + (long)(m0 + half * 128 + row) * lda + t * 64 + (kb >> 1),
                  (void*)(dst + c * 8));
    }
  };
  auto stB = [&](int t, int half) {
    u16* dst = lds + (size_t)(t & 1) * SLOT + A_EL + half * 8192;
#pragma unroll
    for (int i = 0; i < 2; ++i) {
      const int c = tid + i * 512;
      const int row = c >> 3;
      const int kb = ((c & 7) << 4) ^ ((row & 7) << 4);
      gload_lds16(Bb + (long)(n0 + half * 128 + row) * ldb + t * 64 + (kb >> 1),
                  (void*)(dst + c * 8));
    }
  };

  short8 bf[8];  // nf(4) x kh(2), read once per tile in its q0 phase
  auto ld_b = [&](const u16* B_) {
#pragma unroll
    for (int nf = 0; nf < 4; ++nf)
#pragma unroll
      for (int kh = 0; kh < 2; ++kh)
        bf[nf * 2 + kh] = *(const short8*)(B_ + (wc * 64 + nf * 16 + l15) * 64 +
                                           (((kh * 64 + lhi * 16) ^ sl) >> 1));
  };
  auto ld_aq = [&](short8 (&af)[2][2], const u16* A_, int q) {
#pragma unroll
    for (int i = 0; i < 2; ++i)
#pragma unroll
      for (int kh = 0; kh < 2; ++kh)
        af[i][kh] = *(const short8*)(A_ + (wr * WROWS + (q * 2 + i) * 16 + l15) * 64 +
                                     (((kh * 64 + lhi * 16) ^ sl) >> 1));
  };
  auto mfma16 = [&](short8 (&af)[2][2], int q) {
    __builtin_amdgcn_s_setprio(1);
#pragma unroll
    for (int kh = 0; kh < 2; ++kh)
#pragma unroll
      for (int i = 0; i < 2; ++i)
#pragma unroll
        for (int nf = 0; nf < 4; ++nf)
          acc[q * 2 + i][nf] = __builtin_amdgcn_mfma_f32_16x16x32_bf16(
              af[i][kh], bf[nf * 2 + kh], acc[q * 2 + i][nf], 0, 0, 0);
    __builtin_amdgcn_s_setprio(0);
  };

  // ---- prologue: A(0), B(0), B(1); gate leaves B(1) in flight ----
  stA(0, 0); stA(0, 1);
  if constexpr (BN_ == 256) { stB(0, 0); stB(0, 1); stB(1, 0); stB(1, 1); }
  else                      { stB(0, 0); stB(1, 0); }
  if constexpr (BN_ == 256) { asm volatile("s_waitcnt vmcnt(4)" ::: "memory"); }
  else                      { asm volatile("s_waitcnt vmcnt(2)" ::: "memory"); }
  SCB;
  __builtin_amdgcn_s_barrier();
  SCB;

  for (int I = 0; I < halfT; ++I) {
    const int e = 2 * I;
    const bool full = (I < halfT - 1);
    const u16* Ae = lds;
    const u16* Be = lds + A_EL;
    const u16* Ao = lds + SLOT;
    const u16* Bo = lds + SLOT + A_EL;
    short8 af[2][2];

    if constexpr (BN_ == 256) {
      // even tile, 4 phases
      ld_b(Be); ld_aq(af, Ae, 0); stA(e + 1, 0);
      PH_MID; mfma16(af, 0); PH_END;
      ld_aq(af, Ae, 1); stA(e + 1, 1);
      PH_MID; mfma16(af, 1); PH_END;
      ld_aq(af, Ae, 2); if (full) stB(e + 2, 0);
      PH_MID; mfma16(af, 2); PH_END;
      ld_aq(af, Ae, 3); if (full) stB(e + 2, 1);
      if (full) { asm volatile("s_waitcnt vmcnt(4)" ::: "memory"); }
      else      { asm volatile("s_waitcnt vmcnt(0)" ::: "memory"); }
      PH_MID; mfma16(af, 3); PH_END;
      // odd tile, 4 phases
      ld_b(Bo); ld_aq(af, Ao, 0); if (full) stA(e + 2, 0);
      PH_MID; mfma16(af, 0); PH_END;
      ld_aq(af, Ao, 1); if (full) stA(e + 2, 1);
      PH_MID; mfma16(af, 1); PH_END;
      ld_aq(af, Ao, 2); if (full) stB(e + 3, 0);
      PH_MID; mfma16(af, 2); PH_END;
      ld_aq(af, Ao, 3); if (full) stB(e + 3, 1);
      if (full) { asm volatile("s_waitcnt vmcnt(4)" ::: "memory"); }
      PH_MID; mfma16(af, 3); PH_END;
    } else {
      // even tile, 2 phases
      ld_b(Be); ld_aq(af, Ae, 0); stA(e + 1, 0); stA(e + 1, 1);
      PH_MID; mfma16(af, 0); PH_END;
      ld_aq(af, Ae, 1); if (full) stB(e + 2, 0);
      if (full) { asm volatile("s_waitcnt vmcnt(2)" ::: "memory"); }
      else      { asm volatile("s_waitcnt vmcnt(0)" ::: "memory"); }
      PH_MID; mfma16(af, 1); PH_END;
      // odd tile, 2 phases
      ld_b(Bo); ld_aq(af, Ao, 0); if (full) { stA(e + 2, 0); stA(e + 2, 1); }
      PH_MID; mfma16(af, 0); PH_END;
      ld_aq(af, Ao, 1); if (full) stB(e + 3, 0);
      if (full) { asm volatile("s_waitcnt vmcnt(2)" ::: "memory"); }
      PH_MID; mfma16(af, 1); PH_END;
    }
  }

  // epilogue: D row=(lane>>4)*4+reg (m), col=lane&15 (n); plain stores (L2-merged)
  const int rbase = m0 + wr * WROWS + lhi * 4;
  const int cbase = n0 + wc * 64 + l15;
#pragma unroll
  for (int mf = 0; mf < MF; ++mf) {
#pragma unroll
    for (int nf = 0; nf < 4; ++nf) {
#pragma unroll
      for (int i = 0; i < 4; ++i) {
        const int row = rbase + mf * 16 + i;
        const int col = cbase + nf * 16;
        const long oidx = (long)b * sOut + (long)row * ldo + col;
        const float v = acc[mf][nf][i];
        if (MODE == 0) {
          ((u16*)OutV)[oidx] = f2bf(v + bias[col]);
        } else if (MODE == 1) {
          ((u16*)OutV)[oidx] = f2bf(v + bias[row]);
        } else if (MODE == 2) {
          ((u16*)OutV)[oidx] = f2bf(v * scale);
        } else if (MODE == 3) {
          ((u16*)OutV)[oidx] = f2bf(v);
        } else {
          const float r = resid[(long)b * sRes + (long)row * ldo + col];
          ((float*)OutV)[oidx] = v + bias[row] + r;
        }
      }
    }
  }
}

// per-(b,g) mean/rstd over contiguous 16*2048 = 32768 floats
__global__ __launch_bounds__(256) void gn_stats(const float* __restrict__ x,
                                                float* __restrict__ stats) {
  const int bg = blockIdx.x;
  const float4* p4 = (const float4*)(x + (long)bg * 32768);
  float s = 0.f, ss = 0.f;
  for (int i = threadIdx.x; i < 8192; i += 256) {
    const float4 u = p4[i];
    s += (u.x + u.y) + (u.z + u.w);
    ss += (u.x * u.x + u.y * u.y) + (u.z * u.z + u.w * u.w);
  }
#pragma unroll
  for (int off = 32; off > 0; off >>= 1) {
    s += __shfl_xor(s, off, 64);
    ss += __shfl_xor(ss, off, 64);
  }
  __shared__ float rs[4], rss[4];
  const int lane = threadIdx.x & 63, wid = threadIdx.x >> 6;
  if (lane == 0) { rs[wid] = s; rss[wid] = ss; }
  __syncthreads();
  if (threadIdx.x == 0) {
    s = rs[0] + rs[1] + rs[2] + rs[3];
    ss = rss[0] + rss[1] + rss[2] + rss[3];
    const float mean = s * (1.f / 32768.f);
    const float var = ss * (1.f / 32768.f) - mean * mean;
    stats[bg * 2] = mean;
    stats[bg * 2 + 1] = rsqrtf(var + 1e-6f);
  }
}

// normalize + affine, write hT[b][n][c] bf16 (64x64 LDS-tiled transpose)
__global__ __launch_bounds__(256) void gn_apply_t(
    const float* __restrict__ x, const float* __restrict__ stats,
    const float* __restrict__ gamma, const float* __restrict__ beta,
    u16* __restrict__ hT) {
  const int b = blockIdx.z, c0 = blockIdx.y * 64, n0 = blockIdx.x * 64;
  __shared__ u16 t[64][72];
  const int tid = threadIdx.x;
  const float* px = x + ((long)b * 512 + c0) * 2048 + n0;
#pragma unroll
  for (int i = 0; i < 4; ++i) {
    const int idx = tid + i * 256;
    const int r = idx >> 4, q4 = (idx & 15) * 4;
    const float4 u = *(const float4*)(px + (long)r * 2048 + q4);
    const int c = c0 + r, g = c >> 4;
    const float mean = stats[(b * 32 + g) * 2];
    const float rstd = stats[(b * 32 + g) * 2 + 1];
    const float ga = gamma[c] * rstd;
    const float be = beta[c] - mean * ga;
    t[r][q4 + 0] = f2bf(u.x * ga + be);
    t[r][q4 + 1] = f2bf(u.y * ga + be);
    t[r][q4 + 2] = f2bf(u.z * ga + be);
    t[r][q4 + 3] = f2bf(u.w * ga + be);
  }
  __syncthreads();
#pragma unroll
  for (int i = 0; i < 2; ++i) {
    const int idx = tid + i * 256;
    const int nr = idx >> 3, cc = (idx & 7) * 8;
    short8 w;
#pragma unroll
    for (int j = 0; j < 8; ++j) w[j] = (short)t[cc + j][nr];
    *(short8*)(hT + ((long)b * 2048 + n0 + nr) * 512 + c0 + cc) = w;
  }
}

// row softmax in place on bf16 S; gid = r*8 + b, row = b*2048 + r (XCD-pinned)
__global__ __launch_bounds__(256) void softmax_rows(u16* __restrict__ S) {
  const int gid = blockIdx.x;
  const long row = (long)(gid & 7) * 2048 + (gid >> 3);
  u16* p = S + row * 2048;
  const int tid = threadIdx.x;
  const int lane = tid & 63, wid = tid >> 6;
  const short8 raw = *(const short8*)(p + tid * 8);
  float v[8];
#pragma unroll
  for (int j = 0; j < 8; ++j) v[j] = bf2f((u16)raw[j]);
  float m = v[0];
#pragma unroll
  for (int j = 1; j < 8; ++j) m = fmaxf(m, v[j]);
#pragma unroll
  for (int off = 32; off > 0; off >>= 1) m = fmaxf(m, __shfl_xor(m, off, 64));
  __shared__ float redm[4], reds[4];
  if (lane == 0) redm[wid] = m;
  __syncthreads();
  m = fmaxf(fmaxf(redm[0], redm[1]), fmaxf(redm[2], redm[3]));
  float e[8];
  float s = 0.f;
#pragma unroll
  for (int j = 0; j < 8; ++j) {
    e[j] = __expf(v[j] - m);
    s += e[j];
  }
#pragma unroll
  for (int off = 32; off > 0; off >>= 1) s += __shfl_xor(s, off, 64);
  if (lane == 0) reds[wid] = s;
  __syncthreads();
  s = reds[0] + reds[1] + reds[2] + reds[3];
  const float inv = 1.f / s;
  short8 o;
#pragma unroll
  for (int j = 0; j < 8; ++j) o[j] = (short)f2bf(e[j] * inv);
  *(short8*)(p + tid * 8) = o;
}

// convert the 4 fp32 512x512 weights to bf16 (contiguous -> wq|wk|wv|wp)
__global__ __launch_bounds__(256) void cvt_w(const float* __restrict__ w0,
                                             const float* __restrict__ w1,
                                             const float* __restrict__ w2,
                                             const float* __restrict__ w3,
                                             u16* __restrict__ out) {
  const int z = blockIdx.y;
  const float* src = (z == 0) ? w0 : (z == 1) ? w1 : (z == 2) ? w2 : w3;
  const int i = blockIdx.x * 256 + threadIdx.x;
  out[(long)z * 262144 + i] = f2bf(src[i]);
}

// concat bq|bk -> bqk[1024]
__global__ __launch_bounds__(256) void cvt_bias(const float* __restrict__ bq,
                                                const float* __restrict__ bk,
                                                float* __restrict__ bqk) {
  const int i = blockIdx.x * 256 + threadIdx.x;
  bqk[i] = (i < 512) ? bq[i] : bk[i - 512];
}

extern "C" void kernel_launch(void* const* d_in, const int* in_sizes, int n_in,
                              void* d_out, int out_size, void* d_ws, size_t ws_size,
                              hipStream_t stream) {
  const float* x = (const float*)d_in[0];
  const float* gs = (const float*)d_in[1];
  const float* gb = (const float*)d_in[2];
  const float* wq = (const float*)d_in[3];
  const float* bq = (const float*)d_in[4];
  const float* wk = (const float*)d_in[5];
  const float* bk = (const float*)d_in[6];
  const float* wv = (const float*)d_in[7];
  const float* bv = (const float*)d_in[8];
  const float* wp = (const float*)d_in[9];
  const float* bp = (const float*)d_in[10];

  char* ws = (char*)d_ws;
  float* stats = (float*)ws;               // 2 KB
  float* bqk = (float*)(ws + 4096);        // 4 KB
  u16* hT = (u16*)(ws + 8192);             // [16384, 512] bf16, 16 MB
  u16* qkT = hT + 8388608;                 // [16384, 1024] bf16, 32 MB (q|k)
  u16* vv = qkT + 16777216;                // [B, 512, 2048] bf16, 16 MB
  u16* S = vv + 8388608;                   // [B, 2048, 2048] bf16, 64 MB
  u16* wb = S + 33554432;                  // wq|wk|wv|wp bf16, 2 MB
  u16* attnT = hT;                         // alias: hT dead after qk + v GEMMs
  float* out = (float*)d_out;

  cvt_w<<<dim3(1024, 4, 1), 256, 0, stream>>>(wq, wk, wv, wp, wb);
  cvt_bias<<<dim3(4), 256, 0, stream>>>(bq, bk, bqk);
  gn_stats<<<dim3(256), 256, 0, stream>>>(x, stats);
  gn_apply_t<<<dim3(32, 8, 8), 256, 0, stream>>>(x, stats, gs, gb, hT);

  // qk: M=16384 (m0=by*256+b*2048), N=1024, K=512; per-b 8m x 4n -> 256 blocks
  gemm10<0, 256><<<dim3(256), 512, 0, stream>>>(
      hT, wb, qkT, bqk, nullptr, 512, 512, 512, 1024, 4, 2048, 0, 0, 0, 0, 0.f);
  // v: M=512, N=2048, K=512; per-b 2m x 16n -> 256 blocks
  gemm10<1, 128><<<dim3(256), 512, 0, stream>>>(
      wb + 524288, hT, vv, bv, nullptr, 512, 512, 512, 2048, 16, 0, 0, 1048576, 1048576, 0, 0.f);
  // S: M=N=2048, K=512; per-b 8m x 8n -> 512 blocks
  gemm10<2, 256><<<dim3(512), 512, 0, stream>>>(
      qkT, qkT + 512, S, nullptr, nullptr, 512, 1024, 1024, 2048, 8, 0, 2097152, 2097152,
      4194304, 0, 0.04419417382415922f);
  softmax_rows<<<dim3(16384), 256, 0, stream>>>(S);
  // PV: M=2048, N=512, K=2048; per-b 8m x 4n -> 256 blocks
  gemm10<3, 128><<<dim3(256), 512, 0, stream>>>(
      S, vv, attnT, nullptr, nullptr, 2048, 2048, 2048, 512, 4, 0, 4194304, 1048576,
      1048576, 0, 0.f);
  // proj+residual: M=512, N=2048, K=512; per-b 2m x 16n -> 256 blocks
  gemm10<4, 128><<<dim3(256), 512, 0, stream>>>(
      wb + 786432, attnT, out, bp, x, 512, 512, 512, 2048, 16, 0, 0, 1048576, 1048576,
      1048576, 0.f);
}